// Round 48
// baseline (198.860 us; speedup 1.0000x reference)
//
#include <hip/hip_runtime.h>

#define DIM 2048
#define BAND 11
#define ROWS 4          // output rows per block
#define NA 26           // A rows staged: r0-11 .. r0+14
#define NH 12           // H0 rows staged: r0-4 .. r0+7

__device__ double g_frob;        // zero-init at load; reset by diag pass each call
__device__ double g_diag[DIM];

__device__ __forceinline__ bool is_prime(int n){
    if (n < 2) return false;
    if (n < 4) return true;
    if ((n & 1) == 0) return false;
    for (int d = 3; d * d <= n; d += 2)
        if (n % d == 0) return false;
    return true;
}
__device__ __forceinline__ bool isp100(int n){ return n <= 541 && is_prime(n); }
__device__ __forceinline__ bool isp20 (int n){ return n <= 71  && is_prime(n); }

__device__ __forceinline__ double A_val(int i, int j, double theta){
    const double PI = 3.14159265358979323846;
    if (j < 0 || j >= DIM) return 0.0;
    int d = i - j; if (d < 0) d = -d;
    if (d == 0){
        double x = 2.0 * PI * (double)i / (double)DIM;
        return theta * cos(x) + theta * cos(2.0 * x) / 2.0 + theta * cos(4.0 * x) / 4.0;
    }
    int lo = (i < j) ? i : j;
    double b = PI * (double)(2 * lo + d) / (double)DIM;
    double s = 0.0;
    if (d <= 1) s += theta * exp(-(double)d / 10.0) * sin(b);
    if (d <= 2) s += theta * exp(-(double)d / 20.0) * sin(2.0 * b) / 2.0;
    s += theta * exp(-(double)d / 40.0) * sin(4.0 * b) / 4.0;
    return s;
}

// K1: stage A band + H0 band in LDS, compute full band (re for output+diag,
// im for frob), write all 2048*4 floats per block (zeros off-band).
__global__ __launch_bounds__(256) void fused_kernel(const double* sr_p,
                                                    const double* si_p,
                                                    const double* th_p,
                                                    float4* out){
    __shared__ double sA[NA][9];
    __shared__ double sDre[NH];      // H0 diag real
    __shared__ double sIm[NH][7];    // H0 imag band, slot o+3

    const int r0 = blockIdx.x * ROWS;
    const double PI = 3.14159265358979323846;
    const double s_re = sr_p[0], s_im = si_p[0], theta = th_p[0];
    const double abs_s = sqrt(s_re * s_re + s_im * s_im);

    // ---- Phase 1: staging (318 tasks) ----
    for (int t = threadIdx.x; t < NA * 9 + NH + 2 * (NH * 3); t += 256){
        if (t < NA * 9){
            int rl = t / 9, u = t % 9;
            int n = r0 - BAND + rl;
            sA[rl][u] = (n >= 0 && n < DIM) ? A_val(n, n - 4 + u, theta) : 0.0;
        } else if (t < NA * 9 + NH){
            int rl = t - NA * 9;
            int n = r0 - 4 + rl;
            double hr = 0.0, hi = 0.0;
            if (n >= 0 && n < DIM){
                double nn = (double)(n + 1);
                double ln_n = log(nn);
                double mag = exp(-s_re * ln_n);
                double ang = s_im * ln_n;
                hr = mag * cos(ang);
                hi = -mag * sin(ang);
                if (isp100(n + 1)) hr += theta * ln_n * ((PI * PI / 6.0) / nn);
            }
            sDre[rl] = hr;
            sIm[rl][3] = hi;
        } else if (t < NA * 9 + NH + NH * 3){
            int idx = t - (NA * 9 + NH);
            int rl = idx / 3, o = idx % 3 + 1;      // upper: slot 3+o
            int n = r0 - 4 + rl;
            double v = 0.0;
            if (n >= 0 && n + o < DIM && isp100(n + 1))
                v = theta * log((double)(n + 1)) / (2.0 * (double)o);
            sIm[rl][3 + o] = v;
        } else {
            int idx = t - (NA * 9 + NH + NH * 3);
            int rl = idx / 3, o = idx % 3 + 1;      // lower: slot 3-o
            int n = r0 - 4 + rl;
            double v = 0.0;
            int c = n - o;
            if (n < DIM && c >= 0 && isp100(c + 1))
                v = -theta * log((double)(c + 1)) / (2.0 * (double)o);
            sIm[rl][3 - o] = v;
        }
    }
    __syncthreads();

    // ---- Phase 2: 4 rows x 512 float4 per block ----
    double loc = 0.0;
    for (int k = 0; k < (ROWS * 512) / 256; ++k){
        int p  = threadIdx.x + k * 256;
        int rl = p >> 9;
        int c4 = p & 511;
        int i  = r0 + rl;
        int c0 = c4 * 4;
        float4 vo = make_float4(0.f, 0.f, 0.f, 0.f);
        if (c0 + 3 >= i - BAND && c0 <= i + BAND){
            float vals[4] = {0.f, 0.f, 0.f, 0.f};
            for (int q = 0; q < 4; ++q){
                int j  = c0 + q;
                int dd = j - i;
                if (j >= DIM || dd < -BAND || dd > BAND) continue;
                const double* ai = sA[rl + BAND];
                const double* aj = sA[j - r0 + BAND];

                double h1r = 0.0, h1i = 0.0, htr = 0.0, hti = 0.0;
                #pragma unroll
                for (int uu = 0; uu < 9; ++uu){
                    int u = i - 4 + uu;
                    if (u < 0 || u >= DIM) continue;
                    double aiu = ai[uu];
                    int hrow = rl + uu;              // u - (r0-4)
                    #pragma unroll
                    for (int vv = 0; vv < 9; ++vv){
                        int v = j - 4 + vv;
                        if (v < 0 || v >= DIM) continue;
                        int o = v - u;
                        if (o < -3 || o > 3) continue;
                        double hr = (o == 0) ? sDre[hrow] : 0.0;  // off-diag re exactly 0
                        double hi = sIm[hrow][o + 3];
                        double w = aiu * aj[vv];
                        h1r += w * hr;
                        h1i += w * hi;
                        htr += w * hr;
                        hti += (u == v) ? (w * hi) : (-w * hi);
                    }
                }

                int ad = dd < 0 ? -dd : dd;
                double aim = 0.0;
                if (ad >= 1 && ad <= 4){
                    double cl = theta;
                    for (int qq = 1; qq < ad; ++qq) cl *= theta;
                    cl *= exp(-(double)ad / 5.0);
                    aim = (dd > 0) ? cl : -cl;
                    if (dd == 1 && isp20(i + 1)) aim += theta * log((double)(i + 1));
                    if (dd == -1 && isp20(j + 1)) aim -= theta * log((double)(j + 1));
                }

                double re = 0.5 * (h1r + htr);
                double im = 0.5 * (h1i - hti) + abs_s * aim;

                vals[q] = (float)re;
                if (dd == 0) g_diag[i] = re;
                loc += re * re + im * im;
            }
            vo = make_float4(vals[0], vals[1], vals[2], vals[3]);
        }
        out[(long long)i * 512 + c4] = vo;
    }

    // wave-level frob reduction, one atomic per wave
    double v = loc;
    #pragma unroll
    for (int off = 32; off > 0; off >>= 1)
        v += __shfl_down(v, off, 64);
    if ((threadIdx.x & 63) == 0 && v != 0.0)
        atomicAdd(&g_frob, v);
}

// K2: single block — read frob, reset for replay, write diag = f32(diag + reg).
__global__ void diag_kernel(float* out){
    double frob = g_frob;
    __syncthreads();
    if (threadIdx.x == 0) g_frob = 0.0;
    double reg = sqrt(frob) * 1e-15;
    if (reg < 1e-18) reg = 1e-18;
    for (int i = threadIdx.x; i < DIM; i += 256){
        out[(long long)i * DIM + i] = (float)(g_diag[i] + reg);
    }
}

extern "C" void kernel_launch(void* const* d_in, const int* in_sizes, int n_in,
                              void* d_out, int out_size, void* d_ws, size_t ws_size,
                              hipStream_t stream){
    const double* sr = (const double*)d_in[0];
    const double* si = (const double*)d_in[1];
    const double* th = (const double*)d_in[2];

    fused_kernel<<<DIM / ROWS, 256, 0, stream>>>(sr, si, th, (float4*)d_out);
    diag_kernel<<<1, 256, 0, stream>>>((float*)d_out);
}

// Round 49
// 28.795 us; speedup vs baseline: 6.9060x; 6.9060x over previous
//
#include <hip/hip_runtime.h>

#define DIM 2048
#define BAND 11
#define ROWS 4          // output rows per block
#define NA 26           // A rows staged: r0-11 .. r0+14
#define NH 12           // H0 rows staged: r0-4 .. r0+7

__device__ double g_frob;        // zero-init at load; reset by diag pass each call
__device__ double g_diag[DIM];

__device__ __forceinline__ bool is_prime(int n){
    if (n < 2) return false;
    if (n < 4) return true;
    if ((n & 1) == 0) return false;
    for (int d = 3; d * d <= n; d += 2)
        if (n % d == 0) return false;
    return true;
}
__device__ __forceinline__ bool isp100(int n){ return n <= 541 && is_prime(n); }
__device__ __forceinline__ bool isp20 (int n){ return n <= 71  && is_prime(n); }

__device__ __forceinline__ double A_val(int i, int j, double theta){
    const double PI = 3.14159265358979323846;
    if (j < 0 || j >= DIM) return 0.0;
    int d = i - j; if (d < 0) d = -d;
    if (d == 0){
        double x = 2.0 * PI * (double)i / (double)DIM;
        return theta * cos(x) + theta * cos(2.0 * x) / 2.0 + theta * cos(4.0 * x) / 4.0;
    }
    int lo = (i < j) ? i : j;
    double b = PI * (double)(2 * lo + d) / (double)DIM;
    double s = 0.0;
    if (d <= 1) s += theta * exp(-(double)d / 10.0) * sin(b);
    if (d <= 2) s += theta * exp(-(double)d / 20.0) * sin(2.0 * b) / 2.0;
    s += theta * exp(-(double)d / 40.0) * sin(4.0 * b) / 4.0;
    return s;
}

// K1: stage A/H0 bands in LDS; one thread per band entry; zero-fill rest.
__global__ __launch_bounds__(256) void fused_kernel(const double* sr_p,
                                                    const double* si_p,
                                                    const double* th_p,
                                                    float* out){
    __shared__ double sA[NA][9];
    __shared__ double sDre[NH];      // H0 diag real
    __shared__ double sIm[NH][7];    // H0 imag band, slot o+3

    const int r0 = blockIdx.x * ROWS;
    const double PI = 3.14159265358979323846;
    const double s_re = sr_p[0], s_im = si_p[0], theta = th_p[0];
    const double abs_s = sqrt(s_re * s_re + s_im * s_im);
    const int tid = threadIdx.x;

    // ---- Phase 1: staging (318 tasks) ----
    for (int t = tid; t < NA * 9 + NH + 2 * (NH * 3); t += 256){
        if (t < NA * 9){
            int rl = t / 9, u = t % 9;
            int n = r0 - BAND + rl;
            sA[rl][u] = (n >= 0 && n < DIM) ? A_val(n, n - 4 + u, theta) : 0.0;
        } else if (t < NA * 9 + NH){
            int rl = t - NA * 9;
            int n = r0 - 4 + rl;
            double hr = 0.0, hi = 0.0;
            if (n >= 0 && n < DIM){
                double nn = (double)(n + 1);
                double ln_n = log(nn);
                double mag = exp(-s_re * ln_n);
                double ang = s_im * ln_n;
                hr = mag * cos(ang);
                hi = -mag * sin(ang);
                if (isp100(n + 1)) hr += theta * ln_n * ((PI * PI / 6.0) / nn);
            }
            sDre[rl] = hr;
            sIm[rl][3] = hi;
        } else if (t < NA * 9 + NH + NH * 3){
            int idx = t - (NA * 9 + NH);
            int rl = idx / 3, o = idx % 3 + 1;      // upper: slot 3+o
            int n = r0 - 4 + rl;
            double v = 0.0;
            if (n >= 0 && n + o < DIM && isp100(n + 1))
                v = theta * log((double)(n + 1)) / (2.0 * (double)o);
            sIm[rl][3 + o] = v;
        } else {
            int idx = t - (NA * 9 + NH + NH * 3);
            int rl = idx / 3, o = idx % 3 + 1;      // lower: slot 3-o
            int n = r0 - 4 + rl;
            double v = 0.0;
            int c = n - o;
            if (n < DIM && c >= 0 && isp100(c + 1))
                v = -theta * log((double)(c + 1)) / (2.0 * (double)o);
            sIm[rl][3 - o] = v;
        }
    }
    __syncthreads();

    double loc = 0.0;

    if (tid < ROWS * 23){
        // ---- Phase 2a: ONE band entry per thread ----
        int rl  = tid / 23;
        int off = tid % 23;
        int i   = r0 + rl;
        int j   = i + off - BAND;
        if (j >= 0 && j < DIM){
            const double* ai = sA[rl + BAND];
            const double* aj = sA[j - r0 + BAND];

            double h1r = 0.0, h1i = 0.0, htr = 0.0, hti = 0.0;
            #pragma unroll
            for (int uu = 0; uu < 9; ++uu){
                int u = i - 4 + uu;
                if (u < 0 || u >= DIM) continue;
                double aiu = ai[uu];
                int hrow = rl + uu;              // u - (r0-4)
                #pragma unroll
                for (int vv = 0; vv < 9; ++vv){
                    int v = j - 4 + vv;
                    if (v < 0 || v >= DIM) continue;
                    int o = v - u;
                    if (o < -3 || o > 3) continue;
                    double hr = (o == 0) ? sDre[hrow] : 0.0;  // off-diag re exactly 0
                    double hi = sIm[hrow][o + 3];
                    double w = aiu * aj[vv];
                    h1r += w * hr;
                    h1i += w * hi;
                    htr += w * hr;
                    hti += (u == v) ? (w * hi) : (-w * hi);
                }
            }

            int dd = j - i;
            int ad = dd < 0 ? -dd : dd;
            double aim = 0.0;
            if (ad >= 1 && ad <= 4){
                double cl = theta;
                for (int qq = 1; qq < ad; ++qq) cl *= theta;
                cl *= exp(-(double)ad / 5.0);
                aim = (dd > 0) ? cl : -cl;
                if (dd == 1 && isp20(i + 1)) aim += theta * log((double)(i + 1));
                if (dd == -1 && isp20(j + 1)) aim -= theta * log((double)(j + 1));
            }

            double re = 0.5 * (h1r + htr);
            double im = 0.5 * (h1i - hti) + abs_s * aim;

            out[(long long)i * DIM + j] = (float)re;
            if (dd == 0) g_diag[i] = re;
            loc = re * re + im * im;
        }
    } else if (tid < ROWS * 23 + ROWS * 6){
        // ---- Phase 2b: ragged zeros in band-straddling float4s ----
        int k = tid - ROWS * 23;
        int rl = k / 6, ridx = k % 6;
        int i = r0 + rl;
        int jlo = i - BAND; if (jlo < 0) jlo = 0;
        int jhi = i + BAND; if (jhi > DIM - 1) jhi = DIM - 1;
        int f0 = jlo >> 2, f1 = jhi >> 2;
        int L = jlo - f0 * 4;
        int R = f1 * 4 + 3 - jhi;
        int j = -1;
        if (ridx < L) j = f0 * 4 + ridx;
        else if (ridx - L < R) j = jhi + 1 + (ridx - L);
        if (j >= 0) out[(long long)i * DIM + j] = 0.0f;
    }

    // ---- Phase 2c: off-band float4 zeros (all threads, coalesced) ----
    float4* out4 = (float4*)out;
    for (int p = tid; p < ROWS * 512; p += 256){
        int rl = p >> 9, f = p & 511;
        int i = r0 + rl;
        int jlo = i - BAND; if (jlo < 0) jlo = 0;
        int jhi = i + BAND; if (jhi > DIM - 1) jhi = DIM - 1;
        int f0 = jlo >> 2, f1 = jhi >> 2;
        if (f < f0 || f > f1)
            out4[(long long)i * 512 + f] = make_float4(0.f, 0.f, 0.f, 0.f);
    }

    // ---- Phase 3: frob wave-reduce + one atomic per wave ----
    double v = loc;
    #pragma unroll
    for (int o = 32; o > 0; o >>= 1)
        v += __shfl_down(v, o, 64);
    if ((tid & 63) == 0 && v != 0.0)
        atomicAdd(&g_frob, v);
}

// K2: single block — read frob, reset for replay, write diag = f32(diag + reg).
__global__ void diag_kernel(float* out){
    double frob = g_frob;
    __syncthreads();
    if (threadIdx.x == 0) g_frob = 0.0;
    double reg = sqrt(frob) * 1e-15;
    if (reg < 1e-18) reg = 1e-18;
    for (int i = threadIdx.x; i < DIM; i += 256){
        out[(long long)i * DIM + i] = (float)(g_diag[i] + reg);
    }
}

extern "C" void kernel_launch(void* const* d_in, const int* in_sizes, int n_in,
                              void* d_out, int out_size, void* d_ws, size_t ws_size,
                              hipStream_t stream){
    const double* sr = (const double*)d_in[0];
    const double* si = (const double*)d_in[1];
    const double* th = (const double*)d_in[2];

    fused_kernel<<<DIM / ROWS, 256, 0, stream>>>(sr, si, th, (float*)d_out);
    diag_kernel<<<1, 256, 0, stream>>>((float*)d_out);
}